// Round 1
// baseline (295.388 us; speedup 1.0000x reference)
//
#include <hip/hip_runtime.h>
#include <hip/hip_bf16.h>
#include <math.h>

#define BB 16
#define SS 2048
#define DD 512
#define MM 256
#define RR 64
#define KK 16

__device__ __forceinline__ float wave_sum(float v) {
#pragma unroll
  for (int off = 32; off > 0; off >>= 1) v += __shfl_xor(v, off);
  return v;
}

__device__ __forceinline__ float sgnf(float v) {
  return (v > 0.f) ? 1.f : ((v < 0.f) ? -1.f : 0.f);
}

// ---------------------------------------------------------------------------
// LN(init_val) -> mv0 [M,D]; pt0[m,r] = (mv0[m]·rUt_w[:,r] + rUt_b[r])*r_w[r]*0.1
// ---------------------------------------------------------------------------
__global__ __launch_bounds__(256) void k_init(
    const float* __restrict__ init_val, const float* __restrict__ ln_g,
    const float* __restrict__ ln_b, const float* __restrict__ rUt_w,
    const float* __restrict__ rUt_b, const float* __restrict__ r_w,
    float* __restrict__ mv0, float* __restrict__ pt0) {
  int m = blockIdx.x, t = threadIdx.x;
  __shared__ float row[DD];
  __shared__ float red[8];
  float x0 = init_val[m * DD + t];
  float x1 = init_val[m * DD + t + 256];
  float s = wave_sum(x0 + x1);
  float sq = wave_sum(x0 * x0 + x1 * x1);
  if ((t & 63) == 0) { red[t >> 6] = s; red[4 + (t >> 6)] = sq; }
  __syncthreads();
  float mean = (red[0] + red[1] + red[2] + red[3]) * (1.0f / DD);
  float var = (red[4] + red[5] + red[6] + red[7]) * (1.0f / DD) - mean * mean;
  float rs = rsqrtf(var + 1e-5f);
  float n0 = (x0 - mean) * rs * ln_g[t] + ln_b[t];
  float n1 = (x1 - mean) * rs * ln_g[t + 256] + ln_b[t + 256];
  mv0[m * DD + t] = n0;
  mv0[m * DD + t + 256] = n1;
  row[t] = n0;
  row[t + 256] = n1;
  __syncthreads();
  if (t < RR) {
    float acc = rUt_b[t];
    for (int d = 0; d < DD; ++d) acc += row[d] * rUt_w[d * RR + t];
    pt0[m * RR + t] = acc * r_w[t] * 0.1f;
  }
}

// ---------------------------------------------------------------------------
// signed_softmax_state over 256 elements per block-row: out = sign*softmax(|x|)*4
// ---------------------------------------------------------------------------
__global__ __launch_bounds__(256) void k_state_softmax(
    const float* __restrict__ in, float* __restrict__ out) {
  int b = blockIdx.x, t = threadIdx.x;
  __shared__ float red[4];
  float v = in[b * MM + t];
  float a = fabsf(v);
  float mx = a;
#pragma unroll
  for (int off = 32; off > 0; off >>= 1) mx = fmaxf(mx, __shfl_xor(mx, off));
  if ((t & 63) == 0) red[t >> 6] = mx;
  __syncthreads();
  mx = fmaxf(fmaxf(red[0], red[1]), fmaxf(red[2], red[3]));
  __syncthreads();
  float e = expf(a - mx);
  float ssum = wave_sum(e);
  if ((t & 63) == 0) red[t >> 6] = ssum;
  __syncthreads();
  ssum = red[0] + red[1] + red[2] + red[3];
  out[b * MM + t] = sgnf(v) * e / ssum * 4.0f;
}

// ---------------------------------------------------------------------------
// C[rows,64] = A[rows,512] @ W[512,64] + bias; optional colscale*(csmul),
// optional rowscale; optional transposed per-batch output [B,64,256].
// Tile 64x64, K-chunks of 64, 256 threads (16x16, 4x4 micro-tile).
// ---------------------------------------------------------------------------
template <bool TRANS_OUT>
__global__ __launch_bounds__(256) void k_gemm512x64(
    const float* __restrict__ A, const float* __restrict__ W,
    const float* __restrict__ bias, const float* __restrict__ colscale,
    float csmul, const float* __restrict__ rowscale, float* __restrict__ C) {
  __shared__ float As[64][65];
  __shared__ float Ws[64][65];
  int tid = threadIdx.x;
  int ty = tid >> 4, tx = tid & 15;
  int row0 = blockIdx.x * 64;
  float acc[4][4] = {};
  for (int kc = 0; kc < DD; kc += 64) {
#pragma unroll
    for (int i = 0; i < 4; ++i) {
      int idx4 = i * 256 + tid;       // 0..1023 float4 slots
      int r = idx4 >> 4;              // 0..63
      int c = (idx4 & 15) << 2;       // 0..60
      float4 va = *reinterpret_cast<const float4*>(
          &A[(size_t)(row0 + r) * DD + kc + c]);
      As[r][c] = va.x; As[r][c + 1] = va.y; As[r][c + 2] = va.z; As[r][c + 3] = va.w;
      float4 vw = *reinterpret_cast<const float4*>(&W[(size_t)(kc + r) * RR + c]);
      Ws[r][c] = vw.x; Ws[r][c + 1] = vw.y; Ws[r][c + 2] = vw.z; Ws[r][c + 3] = vw.w;
    }
    __syncthreads();
#pragma unroll
    for (int k = 0; k < 64; ++k) {
      float a0 = As[ty * 4 + 0][k], a1 = As[ty * 4 + 1][k];
      float a2 = As[ty * 4 + 2][k], a3 = As[ty * 4 + 3][k];
      float b0 = Ws[k][tx * 4 + 0], b1 = Ws[k][tx * 4 + 1];
      float b2 = Ws[k][tx * 4 + 2], b3 = Ws[k][tx * 4 + 3];
      acc[0][0] += a0 * b0; acc[0][1] += a0 * b1; acc[0][2] += a0 * b2; acc[0][3] += a0 * b3;
      acc[1][0] += a1 * b0; acc[1][1] += a1 * b1; acc[1][2] += a1 * b2; acc[1][3] += a1 * b3;
      acc[2][0] += a2 * b0; acc[2][1] += a2 * b1; acc[2][2] += a2 * b2; acc[2][3] += a2 * b3;
      acc[3][0] += a3 * b0; acc[3][1] += a3 * b1; acc[3][2] += a3 * b2; acc[3][3] += a3 * b3;
    }
    __syncthreads();
  }
#pragma unroll
  for (int i = 0; i < 4; ++i) {
    int rr = row0 + ty * 4 + i;
#pragma unroll
    for (int j = 0; j < 4; ++j) {
      int cc = tx * 4 + j;
      float v = acc[i][j] + bias[cc];
      if (colscale) v *= colscale[cc] * csmul;
      if (rowscale) v *= rowscale[rr];
      if (TRANS_OUT) {
        int b = rr >> 8;   // / M
        int mm = rr & 255; // % M
        C[((size_t)b * RR + cc) * MM + mm] = v;
      } else {
        C[(size_t)rr * RR + cc] = v;
      }
    }
  }
}

// ---------------------------------------------------------------------------
// scores[b,m,j] = pt0[m,:]·ps[b,j,:]   (K=64). Tile 64m x 64j.
// ---------------------------------------------------------------------------
__global__ __launch_bounds__(256) void k_scores(
    const float* __restrict__ pt0, const float* __restrict__ ps,
    float* __restrict__ scores) {
  int b = blockIdx.z;
  int m0 = blockIdx.y * 64;
  int j0 = blockIdx.x * 64;
  __shared__ float Pt[64][65];
  __shared__ float Ps[64][65];
  int tid = threadIdx.x;
  int ty = tid >> 4, tx = tid & 15;
#pragma unroll
  for (int i = 0; i < 4; ++i) {
    int idx4 = i * 256 + tid;
    int r = idx4 >> 4;
    int c = (idx4 & 15) << 2;
    float4 vp = *reinterpret_cast<const float4*>(&pt0[(size_t)(m0 + r) * RR + c]);
    Pt[r][c] = vp.x; Pt[r][c + 1] = vp.y; Pt[r][c + 2] = vp.z; Pt[r][c + 3] = vp.w;
    float4 vs = *reinterpret_cast<const float4*>(
        &ps[((size_t)b * SS + j0 + r) * RR + c]);
    Ps[r][c] = vs.x; Ps[r][c + 1] = vs.y; Ps[r][c + 2] = vs.z; Ps[r][c + 3] = vs.w;
  }
  __syncthreads();
  float acc[4][4] = {};
#pragma unroll
  for (int k = 0; k < 64; ++k) {
    float a0 = Pt[ty * 4 + 0][k], a1 = Pt[ty * 4 + 1][k];
    float a2 = Pt[ty * 4 + 2][k], a3 = Pt[ty * 4 + 3][k];
    float b0 = Ps[tx * 4 + 0][k], b1 = Ps[tx * 4 + 1][k];
    float b2 = Ps[tx * 4 + 2][k], b3 = Ps[tx * 4 + 3][k];
    acc[0][0] += a0 * b0; acc[0][1] += a0 * b1; acc[0][2] += a0 * b2; acc[0][3] += a0 * b3;
    acc[1][0] += a1 * b0; acc[1][1] += a1 * b1; acc[1][2] += a1 * b2; acc[1][3] += a1 * b3;
    acc[2][0] += a2 * b0; acc[2][1] += a2 * b1; acc[2][2] += a2 * b2; acc[2][3] += a2 * b3;
    acc[3][0] += a3 * b0; acc[3][1] += a3 * b1; acc[3][2] += a3 * b2; acc[3][3] += a3 * b3;
  }
  float* obase = scores + (size_t)b * MM * SS;
#pragma unroll
  for (int i = 0; i < 4; ++i) {
#pragma unroll
    for (int j = 0; j < 4; ++j) {
      obase[(size_t)(m0 + ty * 4 + i) * SS + j0 + tx * 4 + j] = acc[i][j];
    }
  }
}

// ---------------------------------------------------------------------------
// Per (b,m): top-16 of |scores row| -> signed-abs-softmax edges -> gather
// token rows -> mem_val row + LN -> mv1; also ms_w = ms0 + sum(e*state).
// ---------------------------------------------------------------------------
__global__ __launch_bounds__(256) void k_write(
    const float* __restrict__ scores, const float* __restrict__ token_val,
    const float* __restrict__ token_state, const float* __restrict__ mv0,
    const float* __restrict__ ms0, const float* __restrict__ ln_g,
    const float* __restrict__ ln_b, float* __restrict__ mv1,
    float* __restrict__ ms_w) {
  int m = blockIdx.x, b = blockIdx.y, t = threadIdx.x;
  const float* srow = scores + ((size_t)b * MM + m) * SS;
  float v[8], a[8];
#pragma unroll
  for (int i = 0; i < 8; ++i) {
    v[i] = srow[t + i * 256];
    a[i] = fabsf(v[i]);
  }
  __shared__ float swv[4];
  __shared__ int swi[4];
  __shared__ int sel_idx[KK];
  __shared__ float sel_val[KK];
  for (int it = 0; it < KK; ++it) {
    float lv = -1.f;
    int li = 0;
#pragma unroll
    for (int i = 0; i < 8; ++i)
      if (a[i] > lv) { lv = a[i]; li = i; }
    int gi = t + li * 256;
#pragma unroll
    for (int off = 32; off > 0; off >>= 1) {
      float ov = __shfl_xor(lv, off);
      int oi = __shfl_xor(gi, off);
      if (ov > lv || (ov == lv && oi < gi)) { lv = ov; gi = oi; }
    }
    if ((t & 63) == 0) { swv[t >> 6] = lv; swi[t >> 6] = gi; }
    __syncthreads();
    if (t == 0) {
      float bv = swv[0]; int bi = swi[0];
      for (int w2 = 1; w2 < 4; ++w2)
        if (swv[w2] > bv || (swv[w2] == bv && swi[w2] < bi)) { bv = swv[w2]; bi = swi[w2]; }
      sel_idx[it] = bi;
    }
    __syncthreads();
    int gidx = sel_idx[it];
    if ((gidx & 255) == t) {
      int li2 = gidx >> 8;
      sel_val[it] = v[li2];
      a[li2] = -1.f;
    }
    __syncthreads();
  }
  // signed-abs-softmax over the 16 selected (all threads redundantly)
  float mx = 0.f;
#pragma unroll
  for (int k = 0; k < KK; ++k) mx = fmaxf(mx, fabsf(sel_val[k]));
  float es[KK];
  float ssum = 0.f;
#pragma unroll
  for (int k = 0; k < KK; ++k) {
    float sv = sel_val[k];
    float ex = expf(fabsf(sv) - mx);
    ssum += ex;
    es[k] = sgnf(sv) * ex;
  }
  float inv = 1.f / ssum;
  float acc0 = mv0[m * DD + t];
  float acc1 = mv0[m * DD + t + 256];
  float stacc = 0.f;
#pragma unroll
  for (int k = 0; k < KK; ++k) {
    int j = sel_idx[k];
    float e = es[k] * inv;
    const float* tv = token_val + ((size_t)b * SS + j) * DD;
    acc0 += e * tv[t];
    acc1 += e * tv[t + 256];
    stacc += e * token_state[b * SS + j];
  }
  if (t == 0) ms_w[b * MM + m] = ms0[m] + stacc;
  // LN
  __shared__ float red[8];
  float s = wave_sum(acc0 + acc1);
  float sq = wave_sum(acc0 * acc0 + acc1 * acc1);
  if ((t & 63) == 0) { red[t >> 6] = s; red[4 + (t >> 6)] = sq; }
  __syncthreads();
  float mean = (red[0] + red[1] + red[2] + red[3]) * (1.0f / DD);
  float var = (red[4] + red[5] + red[6] + red[7]) * (1.0f / DD) - mean * mean;
  float rs = rsqrtf(var + 1e-5f);
  float* orow = mv1 + ((size_t)b * MM + m) * DD;
  orow[t] = (acc0 - mean) * rs * ln_g[t] + ln_b[t];
  orow[t + 256] = (acc1 - mean) * rs * ln_g[t + 256] + ln_b[t + 256];
}

// ---------------------------------------------------------------------------
// Per (b,m): pscores[j] = pt1[b,m,:]·ps1T[b,:,j] (ms1 folded into ps1T);
// top-16 -> edges -> gather mv1 rows -> residual -> LN -> out.
// ---------------------------------------------------------------------------
__global__ __launch_bounds__(256) void k_prop(
    const float* __restrict__ pt1, const float* __restrict__ ps1T,
    const float* __restrict__ mv1, const float* __restrict__ ln_g,
    const float* __restrict__ ln_b, float* __restrict__ out) {
  int m = blockIdx.x, b = blockIdx.y, t = threadIdx.x;
  __shared__ float ptrow[RR];
  if (t < RR) ptrow[t] = pt1[((size_t)b * MM + m) * RR + t];
  __syncthreads();
  const float* pB = ps1T + (size_t)b * RR * MM;
  float sc = 0.f;
#pragma unroll 8
  for (int r = 0; r < RR; ++r) sc += ptrow[r] * pB[r * MM + t];
  float av = fabsf(sc);
  __shared__ float swv[4];
  __shared__ int swi[4];
  __shared__ int sel_idx[KK];
  __shared__ float sel_val[KK];
  for (int it = 0; it < KK; ++it) {
    float lv = av;
    int gi = t;
#pragma unroll
    for (int off = 32; off > 0; off >>= 1) {
      float ov = __shfl_xor(lv, off);
      int oi = __shfl_xor(gi, off);
      if (ov > lv || (ov == lv && oi < gi)) { lv = ov; gi = oi; }
    }
    if ((t & 63) == 0) { swv[t >> 6] = lv; swi[t >> 6] = gi; }
    __syncthreads();
    if (t == 0) {
      float bv = swv[0]; int bi = swi[0];
      for (int w2 = 1; w2 < 4; ++w2)
        if (swv[w2] > bv || (swv[w2] == bv && swi[w2] < bi)) { bv = swv[w2]; bi = swi[w2]; }
      sel_idx[it] = bi;
    }
    __syncthreads();
    int gidx = sel_idx[it];
    if (gidx == t) {
      sel_val[it] = sc;
      av = -1.f;
    }
    __syncthreads();
  }
  float mx = 0.f;
#pragma unroll
  for (int k = 0; k < KK; ++k) mx = fmaxf(mx, fabsf(sel_val[k]));
  float es[KK];
  float ssum = 0.f;
#pragma unroll
  for (int k = 0; k < KK; ++k) {
    float sv = sel_val[k];
    float ex = expf(fabsf(sv) - mx);
    ssum += ex;
    es[k] = sgnf(sv) * ex;
  }
  float inv = 1.f / ssum;
  const float* mrow = mv1 + ((size_t)b * MM + m) * DD;
  float acc0 = mrow[t];
  float acc1 = mrow[t + 256];
#pragma unroll
  for (int k = 0; k < KK; ++k) {
    int j = sel_idx[k];
    float e = es[k] * inv;
    const float* pv = mv1 + ((size_t)b * MM + j) * DD;
    acc0 += e * pv[t];
    acc1 += e * pv[t + 256];
  }
  __shared__ float red[8];
  float s = wave_sum(acc0 + acc1);
  float sq = wave_sum(acc0 * acc0 + acc1 * acc1);
  if ((t & 63) == 0) { red[t >> 6] = s; red[4 + (t >> 6)] = sq; }
  __syncthreads();
  float mean = (red[0] + red[1] + red[2] + red[3]) * (1.0f / DD);
  float var = (red[4] + red[5] + red[6] + red[7]) * (1.0f / DD) - mean * mean;
  float rs = rsqrtf(var + 1e-5f);
  float* orow = out + ((size_t)b * MM + m) * DD;
  orow[t] = (acc0 - mean) * rs * ln_g[t] + ln_b[t];
  orow[t + 256] = (acc1 - mean) * rs * ln_g[t + 256] + ln_b[t + 256];
}

extern "C" void kernel_launch(void* const* d_in, const int* in_sizes, int n_in,
                              void* d_out, int out_size, void* d_ws,
                              size_t ws_size, hipStream_t stream) {
  const float* token_val = (const float*)d_in[0];
  const float* token_state = (const float*)d_in[1];
  const float* init_state = (const float*)d_in[2];
  const float* init_val = (const float*)d_in[3];
  const float* rUs_w = (const float*)d_in[4];
  const float* rUs_b = (const float*)d_in[5];
  const float* rUt_w = (const float*)d_in[6];
  const float* rUt_b = (const float*)d_in[7];
  const float* r_w = (const float*)d_in[8];
  const float* pUs_w = (const float*)d_in[9];
  const float* pUs_b = (const float*)d_in[10];
  const float* pUt_w = (const float*)d_in[11];
  const float* pUt_b = (const float*)d_in[12];
  const float* p_w = (const float*)d_in[13];
  const float* ln_g = (const float*)d_in[14];
  const float* ln_b = (const float*)d_in[15];
  float* out = (float*)d_out;

  float* ws = (float*)d_ws;
  float* mv0 = ws;    ws += MM * DD;                 // 131072
  float* pt0 = ws;    ws += MM * RR;                 // 16384
  float* ms0 = ws;    ws += MM;                      // 256
  float* ps = ws;     ws += (size_t)BB * SS * RR;    // 2097152
  float* scores = ws; ws += (size_t)BB * MM * SS;    // 8388608
  float* mv1 = ws;    ws += (size_t)BB * MM * DD;    // 2097152
  float* ms_w = ws;   ws += BB * MM;                 // 4096
  float* ms1 = ws;    ws += BB * MM;                 // 4096
  float* pt1 = ws;    ws += (size_t)BB * MM * RR;    // 262144
  float* ps1T = ws;   ws += (size_t)BB * RR * MM;    // 262144

  k_init<<<MM, 256, 0, stream>>>(init_val, ln_g, ln_b, rUt_w, rUt_b, r_w, mv0, pt0);
  k_state_softmax<<<1, 256, 0, stream>>>(init_state, ms0);
  k_gemm512x64<false><<<(BB * SS) / 64, 256, 0, stream>>>(
      token_val, rUs_w, rUs_b, nullptr, 1.f, nullptr, ps);
  dim3 gs(SS / 64, MM / 64, BB);
  k_scores<<<gs, 256, 0, stream>>>(pt0, ps, scores);
  dim3 gw(MM, BB);
  k_write<<<gw, 256, 0, stream>>>(scores, token_val, token_state, mv0, ms0,
                                  ln_g, ln_b, mv1, ms_w);
  k_state_softmax<<<BB, 256, 0, stream>>>(ms_w, ms1);
  k_gemm512x64<false><<<(BB * MM) / 64, 256, 0, stream>>>(
      mv1, pUt_w, pUt_b, p_w, 0.1f, nullptr, pt1);
  k_gemm512x64<true><<<(BB * MM) / 64, 256, 0, stream>>>(
      mv1, pUs_w, pUs_b, nullptr, 1.f, ms1, ps1T);
  k_prop<<<gw, 256, 0, stream>>>(pt1, ps1T, mv1, ln_g, ln_b, out);
}